// Round 10
// baseline (93.441 us; speedup 1.0000x reference)
//
#include <hip/hip_runtime.h>

// BERT-CRF NER, two kernels.
//  K1 feats (v5): X[65536,768] @ W^T + b -> featsP[65536][16] (row-major,
//     padded to 16 floats -> 64-B-aligned single-transaction stores).
//     ZERO LDS/DS ops. W in VGPRs (156 regs, k-slice layout). X via coalesced
//     float4 loads, 3-row prefetch (store ack + HBM latency hidden behind
//     3 iterations). DPP tree-sum (row_shr 1/2/4/8 + row_bcast 15/31) on the
//     VALU pipe; totals via readlane(63) + cndmask select chain.
//  K2 viterbi: round-4 kernel, staging adapted to the padded row-major layout.
// B=256, T=256, H=768, L=13, START=11.
// Outputs (float32): [0..255] max_p/T; [256..65791] path.

#define NEGV (-10000.0f)

// v += dpp_move(v) entirely on the VALU pipe. ctrl/rmask are literals.
#define DPP_ADD(v, ctrl, rmask)                                               \
  v += __int_as_float(__builtin_amdgcn_update_dpp(                            \
      0, __float_as_int(v), (ctrl), (rmask), 0xF, true));

// full 64-lane sum -> lane 63 holds the total
#define DPP_REDUCE64(v)                                                       \
  DPP_ADD(v, 0x111, 0xF)  /* row_shr:1  */                                    \
  DPP_ADD(v, 0x112, 0xF)  /* row_shr:2  */                                    \
  DPP_ADD(v, 0x114, 0xF)  /* row_shr:4  */                                    \
  DPP_ADD(v, 0x118, 0xF)  /* row_shr:8  */                                    \
  DPP_ADD(v, 0x142, 0xA)  /* row_bcast:15 -> rows 1,3 */                      \
  DPP_ADD(v, 0x143, 0xC)  /* row_bcast:31 -> rows 2,3 */

// ---------------------------------------------------------------- kernel 1 --
// Wave = reduction unit; lane l owns k-slice {4l..4l+3, 256+4l.., 512+4l..}.
// Each wave computes 32 consecutive rows; block (4 waves) = 128 rows.
__global__ __launch_bounds__(256) void feats_kernel(
    const float* __restrict__ X,      // [65536, 768]
    const float* __restrict__ W,      // [13, 768]
    const float* __restrict__ bias,   // [13]
    float* __restrict__ featsP)       // [65536][16] padded row-major
{
  const int tid = threadIdx.x;
  const int w = tid >> 6, l = tid & 63;
  const long row0 = (long)blockIdx.x * 128 + w * 32;

  // W -> VGPRs, k-slice layout (one-time; L2-cached across waves)
  float wreg[13][12];
  #pragma unroll
  for (int col = 0; col < 13; ++col) {
    #pragma unroll
    for (int j = 0; j < 3; ++j) {
      float4 v = *reinterpret_cast<const float4*>(W + col * 768 + 256 * j + 4 * l);
      wreg[col][4 * j + 0] = v.x; wreg[col][4 * j + 1] = v.y;
      wreg[col][4 * j + 2] = v.z; wreg[col][4 * j + 3] = v.w;
    }
  }
  const float bv = bias[(l < 13) ? l : 0];

  const float* xp = X + row0 * 768 + 4 * l;

  // prefetch rows 0,1,2 (9 loads, 9 KB in flight per wave)
  float4 xa0 = *reinterpret_cast<const float4*>(xp);
  float4 xa1 = *reinterpret_cast<const float4*>(xp + 256);
  float4 xa2 = *reinterpret_cast<const float4*>(xp + 512);
  float4 xb0 = *reinterpret_cast<const float4*>(xp + 768);
  float4 xb1 = *reinterpret_cast<const float4*>(xp + 1024);
  float4 xb2 = *reinterpret_cast<const float4*>(xp + 1280);
  float4 xc0 = *reinterpret_cast<const float4*>(xp + 1536);
  float4 xc1 = *reinterpret_cast<const float4*>(xp + 1792);
  float4 xc2 = *reinterpret_cast<const float4*>(xp + 2048);

  #pragma unroll 1
  for (int r = 0; r < 32; ++r) {
    float4 xd0, xd1, xd2;
    if (r < 29) {                       // issue row r+3 loads first
      const float* xn = xp + (r + 3) * 768;
      xd0 = *reinterpret_cast<const float4*>(xn);
      xd1 = *reinterpret_cast<const float4*>(xn + 256);
      xd2 = *reinterpret_cast<const float4*>(xn + 512);
    }

    const float x[12] = {xa0.x, xa0.y, xa0.z, xa0.w,
                         xa1.x, xa1.y, xa1.z, xa1.w,
                         xa2.x, xa2.y, xa2.z, xa2.w};
    float acc[13];
    #pragma unroll
    for (int c = 0; c < 13; ++c) acc[c] = 0.0f;
    #pragma unroll
    for (int col = 0; col < 13; ++col)
      #pragma unroll
      for (int k = 0; k < 12; ++k)
        acc[col] = fmaf(x[k], wreg[col][k], acc[col]);

    // 13 independent DPP tree-sums (VALU pipe only; chains interleave)
    #pragma unroll
    for (int c = 0; c < 13; ++c) {
      DPP_REDUCE64(acc[c])
    }

    // totals live in lane 63; lane c selects its own via cndmask chain
    float v = __uint_as_float(
        __builtin_amdgcn_readlane(__float_as_uint(acc[0]), 63));
    #pragma unroll
    for (int c = 1; c < 13; ++c) {
      float tc = __uint_as_float(
          __builtin_amdgcn_readlane(__float_as_uint(acc[c]), 63));
      v = (l == c) ? tc : v;            // v_cndmask, pure VALU
    }
    v += bv;
    // single-transaction store: 52 B inside one 64-B-aligned line
    if (l < 13) featsP[(row0 + r) * 16 + l] = v;

    xa0 = xb0; xa1 = xb1; xa2 = xb2;    // advance 3-deep pipeline
    xb0 = xc0; xb1 = xc1; xb2 = xc2;
    xc0 = xd0; xc1 = xd1; xc2 = xd2;
  }
}

// ---------------------------------------------------------------- kernel 2 --
// Round-4 kernel; only the fsT staging block changed (padded row-major input).
__global__ __launch_bounds__(256) void viterbi_kernel(
    const float* __restrict__ featsP,  // [65536][16] padded row-major
    const float* __restrict__ trans,   // [13,13]
    float* __restrict__ out)           // [256 + 65536]
{
  __shared__ float fsT[13 * 260];          // feats transposed [to][t] (pad 260)
  __shared__ float lds_ld[256 * 16];       // ld_t[to], t = 0..255
  __shared__ float trL[176];               // trans (169 used)
  __shared__ unsigned char psi[256 * 16];  // psi[t][to]
  __shared__ unsigned char Mm[256];        // [16 chunks][16]
  __shared__ unsigned char bnd[16];
  __shared__ unsigned char path[256];

  const int tid = threadIdx.x;
  const int w = tid >> 6, lane = tid & 63;
  const int b = blockIdx.x;

  {  // stage feats: thread tid owns timestep t=tid (64-B aligned float4 x4)
    const float4* fr = reinterpret_cast<const float4*>(
        featsP + ((long)b * 256 + tid) * 16);
    float4 a0 = fr[0], a1 = fr[1], a2 = fr[2], a3 = fr[3];
    fsT[ 0 * 260 + tid] = a0.x; fsT[ 1 * 260 + tid] = a0.y;
    fsT[ 2 * 260 + tid] = a0.z; fsT[ 3 * 260 + tid] = a0.w;
    fsT[ 4 * 260 + tid] = a1.x; fsT[ 5 * 260 + tid] = a1.y;
    fsT[ 6 * 260 + tid] = a1.z; fsT[ 7 * 260 + tid] = a1.w;
    fsT[ 8 * 260 + tid] = a2.x; fsT[ 9 * 260 + tid] = a2.y;
    fsT[10 * 260 + tid] = a2.z; fsT[11 * 260 + tid] = a2.w;
    fsT[12 * 260 + tid] = a3.x;
  }
  if (tid < 169) trL[tid] = trans[tid];
  __syncthreads();

  // ---- phase 1: serial forward (values only), wave 0, lower half-wave ----
  if (w == 0 && lane < 16) {
    float tr[13];
    #pragma unroll
    for (int f = 0; f < 13; ++f)
      tr[f] = (lane < 13) ? trans[lane * 13 + f] : -1.0e30f;

    const int toc = (lane < 13) ? lane : 0;
    const float* frow = &fsT[toc * 260];

    float ld = (lane == 11) ? 0.0f : NEGV;  // START = 11
    if (lane < 13) lds_ld[lane] = ld;       // t = 0

    float4 F[4], Fn[4];
    #pragma unroll
    for (int q = 0; q < 4; ++q)
      F[q] = *reinterpret_cast<const float4*>(frow + 4 * q);

    #pragma unroll 1
    for (int g = 0; g < 16; ++g) {
      if (g < 15) {
        #pragma unroll
        for (int q = 0; q < 4; ++q)
          Fn[q] = *reinterpret_cast<const float4*>(frow + (g + 1) * 16 + 4 * q);
      }
      const int kLo = (g == 0) ? 1 : 0;     // skip t = 0
      #pragma unroll
      for (int k = 0; k < 16; ++k) {
        if (k < kLo) continue;
        const int t = g * 16 + k;
        float c[13];
        #pragma unroll
        for (int f = 0; f < 13; ++f) {
          float lf = __uint_as_float(
              __builtin_amdgcn_readlane(__float_as_uint(ld), f));
          c[f] = tr[f] + lf;
        }
        float p0 = fmaxf(fmaxf(c[0], c[1]), c[2]);
        float p1 = fmaxf(fmaxf(c[3], c[4]), c[5]);
        float p2 = fmaxf(fmaxf(c[6], c[7]), c[8]);
        float p3 = fmaxf(fmaxf(c[9], c[10]), c[11]);
        float m  = fmaxf(fmaxf(fmaxf(p0, p1), p2), fmaxf(p3, c[12]));

        const float4 fq = F[k >> 2];
        const float ft = ((k & 3) == 0) ? fq.x : ((k & 3) == 1) ? fq.y
                        : ((k & 3) == 2) ? fq.z : fq.w;
        ld = m + ft;
        if (lane < 13) lds_ld[t * 16 + lane] = ld;
      }
      #pragma unroll
      for (int q = 0; q < 4; ++q) F[q] = Fn[q];
    }
  }
  __syncthreads();

  // ---- phase 2: psi in parallel over t ----
  {
    const int to = tid & 15, dtt = tid >> 4;
    if (to < 13) {
      float trr[13];
      #pragma unroll
      for (int f = 0; f < 13; ++f) trr[f] = trL[to * 13 + f];
      for (int t = (dtt == 0 ? 16 : dtt); t < 256; t += 16) {
        const float* lp = &lds_ld[(t - 1) * 16];
        float4 l0 = *reinterpret_cast<const float4*>(lp);
        float4 l1 = *reinterpret_cast<const float4*>(lp + 4);
        float4 l2 = *reinterpret_cast<const float4*>(lp + 8);
        float4 l3 = *reinterpret_cast<const float4*>(lp + 12);
        float c[13] = {trr[0] + l0.x,  trr[1] + l0.y,  trr[2] + l0.z,
                       trr[3] + l0.w,  trr[4] + l1.x,  trr[5] + l1.y,
                       trr[6] + l1.z,  trr[7] + l1.w,  trr[8] + l2.x,
                       trr[9] + l2.y,  trr[10] + l2.z, trr[11] + l2.w,
                       trr[12] + l3.x};
        float best = c[0]; int bf = 0;
        #pragma unroll
        for (int f = 1; f < 13; ++f) {
          bool gt = c[f] > best;              // strict >: first index wins
          best = gt ? c[f] : best;
          bf   = gt ? f : bf;
        }
        psi[t * 16 + to] = (unsigned char)bf;
      }
    }
  }
  __syncthreads();

  // ---- phase 3: ancestor maps ----
  {
    const int sS = tid & 15, g = tid >> 4;
    if (sS < 13) {
      int cur = sS;
      const int tLo = (g == 0) ? 1 : g * 16;
      for (int t = g * 16 + 15; t >= tLo; --t)
        cur = psi[t * 16 + cur];
      Mm[g * 16 + sS] = (unsigned char)cur;
    }
  }
  __syncthreads();

  // ---- phase 4: softmax output + boundary chase ----
  if (tid == 0) {
    const float* lf = &lds_ld[255 * 16];
    float m = lf[0]; int last = 0;
    #pragma unroll
    for (int i = 1; i < 13; ++i)
      if (lf[i] > m) { m = lf[i]; last = i; }   // strict >: first index
    float ssum = 0.0f;
    #pragma unroll
    for (int i = 0; i < 13; ++i) ssum += expf(lf[i] - m);
    out[b] = 1.0f / (256.0f * ssum);            // max(softmax)/T

    int cur = last;
    bnd[15] = (unsigned char)cur;
    #pragma unroll
    for (int cc = 15; cc >= 1; --cc) {
      cur = Mm[cc * 16 + cur];
      bnd[cc - 1] = (unsigned char)cur;
    }
  }
  __syncthreads();

  // ---- phase 5: interior chases ----
  if (tid < 16) {
    int cur = bnd[tid];
    const int tHi = tid * 16 + 15;
    path[tHi] = (unsigned char)cur;
    const int tLo = (tid == 0) ? 1 : tid * 16;
    for (int t = tHi; t >= tLo; --t) {
      cur = psi[t * 16 + cur];
      path[t - 1] = (unsigned char)cur;
    }
  }
  __syncthreads();

  out[256 + (long)b * 256 + tid] = (float)path[tid];
}

// ------------------------------------------------------------------ launch --
extern "C" void kernel_launch(void* const* d_in, const int* in_sizes, int n_in,
                              void* d_out, int out_size, void* d_ws, size_t ws_size,
                              hipStream_t stream) {
  const float* X     = (const float*)d_in[0];
  const float* W     = (const float*)d_in[1];
  const float* bias  = (const float*)d_in[2];
  const float* trans = (const float*)d_in[3];
  float* out    = (float*)d_out;
  float* featsP = (float*)d_ws;   // 65536*16 floats = 4 MB (padded row-major)

  feats_kernel<<<512, 256, 0, stream>>>(X, W, bias, featsP);
  viterbi_kernel<<<256, 256, 0, stream>>>(featsP, trans, out);
}

// Round 11
// 88.126 us; speedup vs baseline: 1.0603x; 1.0603x over previous
//
#include <hip/hip_runtime.h>

// BERT-CRF NER, two kernels.
//  K1 feats (v6): X[65536,768] @ W^T + b -> featsT[13][65536].
//     ZERO DS ops. W in VGPRs (156 regs). 4-deep branchless ring prefetch
//     (unroll 4, unconditional loads, clamped tail index) so the compiler
//     emits COUNTED vmcnt waits instead of per-row vmcnt(0) drains.
//     DPP tree-sum; totals all live in lane 63 -> lane-63 stores 13 dwords
//     (no readlane/cndmask chain).
//  K2 viterbi: byte-identical to round 4/9's passing kernel.
// B=256, T=256, H=768, L=13, START=11.
// Outputs (float32): [0..255] max_p/T; [256..65791] path.

#define NEGV (-10000.0f)

// v += dpp_move(v) entirely on the VALU pipe. ctrl/rmask are literals.
#define DPP_ADD(v, ctrl, rmask)                                               \
  v += __int_as_float(__builtin_amdgcn_update_dpp(                            \
      0, __float_as_int(v), (ctrl), (rmask), 0xF, true));

// full 64-lane sum -> lane 63 holds the total
#define DPP_REDUCE64(v)                                                       \
  DPP_ADD(v, 0x111, 0xF)  /* row_shr:1  */                                    \
  DPP_ADD(v, 0x112, 0xF)  /* row_shr:2  */                                    \
  DPP_ADD(v, 0x114, 0xF)  /* row_shr:4  */                                    \
  DPP_ADD(v, 0x118, 0xF)  /* row_shr:8  */                                    \
  DPP_ADD(v, 0x142, 0xA)  /* row_bcast:15 -> rows 1,3 */                      \
  DPP_ADD(v, 0x143, 0xC)  /* row_bcast:31 -> rows 2,3 */

// ---------------------------------------------------------------- kernel 1 --
// Wave = reduction unit; lane l owns k-slice {4l..4l+3, 256+4l.., 512+4l..}.
// Each wave computes 32 consecutive rows; block (4 waves) = 128 rows.
__global__ __launch_bounds__(256, 2) void feats_kernel(
    const float* __restrict__ X,      // [65536, 768]
    const float* __restrict__ W,      // [13, 768]
    const float* __restrict__ bias,   // [13]
    float* __restrict__ featsT)       // [13][65536]
{
  const int tid = threadIdx.x;
  const int w = tid >> 6, l = tid & 63;
  const long row0 = (long)blockIdx.x * 128 + w * 32;

  // W -> VGPRs, k-slice layout (one-time; L2-cached across waves)
  float wreg[13][12];
  #pragma unroll
  for (int col = 0; col < 13; ++col) {
    #pragma unroll
    for (int j = 0; j < 3; ++j) {
      float4 v = *reinterpret_cast<const float4*>(W + col * 768 + 256 * j + 4 * l);
      wreg[col][4 * j + 0] = v.x; wreg[col][4 * j + 1] = v.y;
      wreg[col][4 * j + 2] = v.z; wreg[col][4 * j + 3] = v.w;
    }
  }
  // bias via uniform (scalar) loads — used only by lane 63's stores
  float bs[13];
  #pragma unroll
  for (int c = 0; c < 13; ++c) bs[c] = bias[c];

  const float* xp = X + row0 * 768 + 4 * l;

  // 4-deep ring prefetch: rows 0..3
  float4 buf[4][3];
  #pragma unroll
  for (int i = 0; i < 4; ++i) {
    buf[i][0] = *reinterpret_cast<const float4*>(xp + i * 768);
    buf[i][1] = *reinterpret_cast<const float4*>(xp + i * 768 + 256);
    buf[i][2] = *reinterpret_cast<const float4*>(xp + i * 768 + 512);
  }

  #pragma unroll 4
  for (int r = 0; r < 32; ++r) {
    const int s = r & 3;                // static after unroll
    const float x[12] = {buf[s][0].x, buf[s][0].y, buf[s][0].z, buf[s][0].w,
                         buf[s][1].x, buf[s][1].y, buf[s][1].z, buf[s][1].w,
                         buf[s][2].x, buf[s][2].y, buf[s][2].z, buf[s][2].w};

    // UNCONDITIONAL refill of this slot (tail clamps to row 31: redundant,
    // harmless, keeps vmcnt countable -> no full drains)
    {
      const int pr = (r + 4 < 32) ? (r + 4) : 31;   // scalar cselect, no branch
      const float* xn = xp + pr * 768;
      buf[s][0] = *reinterpret_cast<const float4*>(xn);
      buf[s][1] = *reinterpret_cast<const float4*>(xn + 256);
      buf[s][2] = *reinterpret_cast<const float4*>(xn + 512);
    }

    float acc[13];
    #pragma unroll
    for (int c = 0; c < 13; ++c) acc[c] = 0.0f;
    #pragma unroll
    for (int col = 0; col < 13; ++col)
      #pragma unroll
      for (int k = 0; k < 12; ++k)
        acc[col] = fmaf(x[k], wreg[col][k], acc[col]);

    // 13 independent DPP tree-sums (VALU pipe only; chains interleave)
    #pragma unroll
    for (int c = 0; c < 13; ++c) {
      DPP_REDUCE64(acc[c])
    }

    // all 13 totals live in lane 63's acc[c] registers: store from lane 63
    if (l == 63) {
      #pragma unroll
      for (int c = 0; c < 13; ++c)
        featsT[(long)c * 65536 + row0 + r] = acc[c] + bs[c];
    }
  }
}

// ---------------------------------------------------------------- kernel 2 --
// (byte-identical to round 4/9's passing viterbi kernel)
__global__ __launch_bounds__(256) void viterbi_kernel(
    const float* __restrict__ featsT,  // [13][65536]
    const float* __restrict__ trans,   // [13,13]
    float* __restrict__ out)           // [256 + 65536]
{
  __shared__ float fsT[13 * 260];          // feats transposed [to][t] (pad 260)
  __shared__ float lds_ld[256 * 16];       // ld_t[to], t = 0..255
  __shared__ float trL[176];               // trans (169 used)
  __shared__ unsigned char psi[256 * 16];  // psi[t][to]
  __shared__ unsigned char Mm[256];        // [16 chunks][16]
  __shared__ unsigned char bnd[16];
  __shared__ unsigned char path[256];

  const int tid = threadIdx.x;
  const int w = tid >> 6, lane = tid & 63;
  const int b = blockIdx.x;

  #pragma unroll
  for (int i = 0; i < 13; ++i)
    fsT[i * 260 + tid] = featsT[(long)i * 65536 + b * 256 + tid];
  if (tid < 169) trL[tid] = trans[tid];
  __syncthreads();

  // ---- phase 1: serial forward (values only), wave 0, lower half-wave ----
  if (w == 0 && lane < 16) {
    float tr[13];
    #pragma unroll
    for (int f = 0; f < 13; ++f)
      tr[f] = (lane < 13) ? trans[lane * 13 + f] : -1.0e30f;

    const int toc = (lane < 13) ? lane : 0;
    const float* frow = &fsT[toc * 260];

    float ld = (lane == 11) ? 0.0f : NEGV;  // START = 11
    if (lane < 13) lds_ld[lane] = ld;       // t = 0

    float4 F[4], Fn[4];
    #pragma unroll
    for (int q = 0; q < 4; ++q)
      F[q] = *reinterpret_cast<const float4*>(frow + 4 * q);

    #pragma unroll 1
    for (int g = 0; g < 16; ++g) {
      if (g < 15) {
        #pragma unroll
        for (int q = 0; q < 4; ++q)
          Fn[q] = *reinterpret_cast<const float4*>(frow + (g + 1) * 16 + 4 * q);
      }
      const int kLo = (g == 0) ? 1 : 0;     // skip t = 0
      #pragma unroll
      for (int k = 0; k < 16; ++k) {
        if (k < kLo) continue;
        const int t = g * 16 + k;
        float c[13];
        #pragma unroll
        for (int f = 0; f < 13; ++f) {
          float lf = __uint_as_float(
              __builtin_amdgcn_readlane(__float_as_uint(ld), f));
          c[f] = tr[f] + lf;
        }
        float p0 = fmaxf(fmaxf(c[0], c[1]), c[2]);
        float p1 = fmaxf(fmaxf(c[3], c[4]), c[5]);
        float p2 = fmaxf(fmaxf(c[6], c[7]), c[8]);
        float p3 = fmaxf(fmaxf(c[9], c[10]), c[11]);
        float m  = fmaxf(fmaxf(fmaxf(p0, p1), p2), fmaxf(p3, c[12]));

        const float4 fq = F[k >> 2];
        const float ft = ((k & 3) == 0) ? fq.x : ((k & 3) == 1) ? fq.y
                        : ((k & 3) == 2) ? fq.z : fq.w;
        ld = m + ft;
        if (lane < 13) lds_ld[t * 16 + lane] = ld;
      }
      #pragma unroll
      for (int q = 0; q < 4; ++q) F[q] = Fn[q];
    }
  }
  __syncthreads();

  // ---- phase 2: psi in parallel over t ----
  {
    const int to = tid & 15, dtt = tid >> 4;
    if (to < 13) {
      float trr[13];
      #pragma unroll
      for (int f = 0; f < 13; ++f) trr[f] = trL[to * 13 + f];
      for (int t = (dtt == 0 ? 16 : dtt); t < 256; t += 16) {
        const float* lp = &lds_ld[(t - 1) * 16];
        float4 l0 = *reinterpret_cast<const float4*>(lp);
        float4 l1 = *reinterpret_cast<const float4*>(lp + 4);
        float4 l2 = *reinterpret_cast<const float4*>(lp + 8);
        float4 l3 = *reinterpret_cast<const float4*>(lp + 12);
        float c[13] = {trr[0] + l0.x,  trr[1] + l0.y,  trr[2] + l0.z,
                       trr[3] + l0.w,  trr[4] + l1.x,  trr[5] + l1.y,
                       trr[6] + l1.z,  trr[7] + l1.w,  trr[8] + l2.x,
                       trr[9] + l2.y,  trr[10] + l2.z, trr[11] + l2.w,
                       trr[12] + l3.x};
        float best = c[0]; int bf = 0;
        #pragma unroll
        for (int f = 1; f < 13; ++f) {
          bool gt = c[f] > best;              // strict >: first index wins
          best = gt ? c[f] : best;
          bf   = gt ? f : bf;
        }
        psi[t * 16 + to] = (unsigned char)bf;
      }
    }
  }
  __syncthreads();

  // ---- phase 3: ancestor maps ----
  {
    const int sS = tid & 15, g = tid >> 4;
    if (sS < 13) {
      int cur = sS;
      const int tLo = (g == 0) ? 1 : g * 16;
      for (int t = g * 16 + 15; t >= tLo; --t)
        cur = psi[t * 16 + cur];
      Mm[g * 16 + sS] = (unsigned char)cur;
    }
  }
  __syncthreads();

  // ---- phase 4: softmax output + boundary chase ----
  if (tid == 0) {
    const float* lf = &lds_ld[255 * 16];
    float m = lf[0]; int last = 0;
    #pragma unroll
    for (int i = 1; i < 13; ++i)
      if (lf[i] > m) { m = lf[i]; last = i; }   // strict >: first index
    float ssum = 0.0f;
    #pragma unroll
    for (int i = 0; i < 13; ++i) ssum += expf(lf[i] - m);
    out[b] = 1.0f / (256.0f * ssum);            // max(softmax)/T

    int cur = last;
    bnd[15] = (unsigned char)cur;
    #pragma unroll
    for (int cc = 15; cc >= 1; --cc) {
      cur = Mm[cc * 16 + cur];
      bnd[cc - 1] = (unsigned char)cur;
    }
  }
  __syncthreads();

  // ---- phase 5: interior chases ----
  if (tid < 16) {
    int cur = bnd[tid];
    const int tHi = tid * 16 + 15;
    path[tHi] = (unsigned char)cur;
    const int tLo = (tid == 0) ? 1 : tid * 16;
    for (int t = tHi; t >= tLo; --t) {
      cur = psi[t * 16 + cur];
      path[t - 1] = (unsigned char)cur;
    }
  }
  __syncthreads();

  out[256 + (long)b * 256 + tid] = (float)path[tid];
}

// ------------------------------------------------------------------ launch --
extern "C" void kernel_launch(void* const* d_in, const int* in_sizes, int n_in,
                              void* d_out, int out_size, void* d_ws, size_t ws_size,
                              hipStream_t stream) {
  const float* X     = (const float*)d_in[0];
  const float* W     = (const float*)d_in[1];
  const float* bias  = (const float*)d_in[2];
  const float* trans = (const float*)d_in[3];
  float* out    = (float*)d_out;
  float* featsT = (float*)d_ws;   // 13*65536 floats = 3.4 MB

  feats_kernel<<<512, 256, 0, stream>>>(X, W, bias, featsT);
  viterbi_kernel<<<256, 256, 0, stream>>>(featsT, trans, out);
}